// Round 1
// baseline (765.664 us; speedup 1.0000x reference)
//
#include <hip/hip_runtime.h>

// ---------------------------------------------------------------------------
// Grouped MLP: h1 = x @ W1^T + b1 ; out = h1 @ W2^T + b2, per group g in [0,8)
// x  [8, 2048, 1024] f32    W1 [8, 4096, 1024] f32   b1 [8, 4096] f32
// W2 [8, 1024, 4096] f32    b2 [8, 1024] f32         out [8, 2048, 1024] f32
//
// Strategy: convert x/W1/W2 to bf16 in ws, run two m97-style bf16 MFMA GEMMs
// (both are A[M,K] x B[N,K] "BT" layout, K contiguous), h1 kept bf16 in ws.
// ---------------------------------------------------------------------------

typedef __bf16 bf16_t;
typedef bf16_t bf16x8 __attribute__((ext_vector_type(8)));
typedef float  floatx4 __attribute__((ext_vector_type(4)));

#define NUM_GEMMS 8
#define HIDDEN 1024
#define INTER 4096
#define MTOK 2048

__device__ __forceinline__ void async_copy16(const bf16_t* gsrc, bf16_t* lds_base) {
  // LDS dest is wave-uniform base + lane*16 (HW semantics); pass wave base.
  __builtin_amdgcn_global_load_lds(
      (const __attribute__((address_space(1))) void*)gsrc,
      (__attribute__((address_space(3))) void*)lds_base,
      16, 0, 0);
}

// fp32 -> bf16, 8 elements per thread (two float4 reads, one 16B write)
__global__ __launch_bounds__(256) void cvt_kernel(const float* __restrict__ src,
                                                  bf16_t* __restrict__ dst,
                                                  int n8) {
  int i = blockIdx.x * 256 + threadIdx.x;
  if (i >= n8) return;
  const float4* s4 = (const float4*)src;
  float4 a = s4[2 * i];
  float4 b = s4[2 * i + 1];
  bf16x8 o;
  o[0] = (bf16_t)a.x; o[1] = (bf16_t)a.y; o[2] = (bf16_t)a.z; o[3] = (bf16_t)a.w;
  o[4] = (bf16_t)b.x; o[5] = (bf16_t)b.y; o[6] = (bf16_t)b.z; o[7] = (bf16_t)b.w;
  *(bf16x8*)(dst + (size_t)i * 8) = o;
}

// C[g,m,n] = sum_k A[g,m,k] * B[g,n,k] + bias[g,n]
// 128x128 tile, BK=32, 256 threads (4 waves, each 64x64 as 4x4 16x16 frags).
template <int M, int N, int K, bool OUT_BF16>
__global__ __launch_bounds__(256) void gemm_bt(const bf16_t* __restrict__ A,
                                               const bf16_t* __restrict__ B,
                                               const float* __restrict__ bias,
                                               void* __restrict__ Cout) {
  constexpr int BM = 128, BN = 128, BK = 32;
  __shared__ bf16_t As[BM * BK];  // 8 KB, row-major [row][k], no padding
  __shared__ bf16_t Bs[BN * BK];  // 8 KB (B^T tile: [n][k])

  const int g  = blockIdx.z;
  const int m0 = blockIdx.x * BM;
  const int n0 = blockIdx.y * BN;

  const bf16_t* Ag = A + (size_t)g * M * K;
  const bf16_t* Bg = B + (size_t)g * N * K;

  const int t    = threadIdx.x;
  const int lane = t & 63;
  const int wave = t >> 6;
  const int wm   = (wave >> 1) * 64;  // wave row offset in C tile
  const int wn   = (wave & 1) * 64;   // wave col offset
  const int l16  = lane & 15;
  const int quad = lane >> 4;

  // Staging map: thread t covers 16B chunk t (rows 0..63) and t+256 (rows 64..127)
  // chunk c = row c/4, cols (c%4)*8 .. +7
  const int sr = t >> 2;
  const int sc = (t & 3) * 8;
  const bf16_t* a0 = Ag + (size_t)(m0 + sr) * K + sc;
  const bf16_t* a1 = a0 + (size_t)64 * K;
  const bf16_t* b0 = Bg + (size_t)(n0 + sr) * K + sc;
  const bf16_t* b1 = b0 + (size_t)64 * K;

  bf16_t* a_lds0 = As + wave * 512;         // wave*1024 bytes
  bf16_t* a_lds1 = As + wave * 512 + 2048;  // +4096 bytes (second half)
  bf16_t* b_lds0 = Bs + wave * 512;
  bf16_t* b_lds1 = Bs + wave * 512 + 2048;

  floatx4 acc[4][4];
  const floatx4 z = {0.0f, 0.0f, 0.0f, 0.0f};
#pragma unroll
  for (int i = 0; i < 4; ++i)
#pragma unroll
    for (int j = 0; j < 4; ++j) acc[i][j] = z;

  for (int kk = 0; kk < K / BK; ++kk) {
    const int kof = kk * BK;
    async_copy16(a0 + kof, a_lds0);
    async_copy16(a1 + kof, a_lds1);
    async_copy16(b0 + kof, b_lds0);
    async_copy16(b1 + kof, b_lds1);
    __syncthreads();  // drains vmcnt (compiler emits full waitcnt before barrier)

    bf16x8 af[4], bfr[4];
#pragma unroll
    for (int i = 0; i < 4; ++i)
      af[i] = *(const bf16x8*)(As + (wm + i * 16 + l16) * BK + quad * 8);
#pragma unroll
    for (int j = 0; j < 4; ++j)
      bfr[j] = *(const bf16x8*)(Bs + (wn + j * 16 + l16) * BK + quad * 8);

#pragma unroll
    for (int i = 0; i < 4; ++i)
#pragma unroll
      for (int j = 0; j < 4; ++j)
        acc[i][j] = __builtin_amdgcn_mfma_f32_16x16x32_bf16(af[i], bfr[j],
                                                            acc[i][j], 0, 0, 0);
    __syncthreads();
  }

  // Epilogue: C/D layout col = lane&15, row = quad*4 + reg (m89/m91 verified)
  const float* bg = bias + (size_t)g * N;
#pragma unroll
  for (int j = 0; j < 4; ++j) {
    const int n  = n0 + wn + j * 16 + l16;
    const float bv = bg[n];
#pragma unroll
    for (int i = 0; i < 4; ++i) {
      const int mr = m0 + wm + i * 16 + quad * 4;
#pragma unroll
      for (int r = 0; r < 4; ++r) {
        const float v = acc[i][j][r] + bv;
        const size_t idx = (size_t)g * M * N + (size_t)(mr + r) * N + n;
        if constexpr (OUT_BF16)
          ((bf16_t*)Cout)[idx] = (bf16_t)v;
        else
          ((float*)Cout)[idx] = v;
      }
    }
  }
}

extern "C" void kernel_launch(void* const* d_in, const int* in_sizes, int n_in,
                              void* d_out, int out_size, void* d_ws, size_t ws_size,
                              hipStream_t stream) {
  const float* x  = (const float*)d_in[0];
  const float* W1 = (const float*)d_in[1];
  const float* b1 = (const float*)d_in[2];
  const float* W2 = (const float*)d_in[3];
  const float* b2 = (const float*)d_in[4];
  float* out = (float*)d_out;

  const size_t nx  = (size_t)NUM_GEMMS * MTOK * HIDDEN;   // 16.7M
  const size_t nw1 = (size_t)NUM_GEMMS * INTER * HIDDEN;  // 33.5M
  const size_t nw2 = nw1;                                 // 33.5M
  // h1: 8 * 2048 * 4096 = 67.1M bf16

  // ws layout (bf16): xb | w1b | w2b | h1  => ~302 MB total
  bf16_t* xb  = (bf16_t*)d_ws;
  bf16_t* w1b = xb + nx;
  bf16_t* w2b = w1b + nw1;
  bf16_t* h1  = w2b + nw2;

  cvt_kernel<<<dim3((unsigned)(nx / 8 / 256)), dim3(256), 0, stream>>>(x, xb, (int)(nx / 8));
  cvt_kernel<<<dim3((unsigned)(nw1 / 8 / 256)), dim3(256), 0, stream>>>(W1, w1b, (int)(nw1 / 8));
  cvt_kernel<<<dim3((unsigned)(nw2 / 8 / 256)), dim3(256), 0, stream>>>(W2, w2b, (int)(nw2 / 8));

  // GEMM1: M=2048, N=4096(INTER), K=1024(HIDDEN) -> h1 (bf16)
  gemm_bt<MTOK, INTER, HIDDEN, true>
      <<<dim3(MTOK / 128, INTER / 128, NUM_GEMMS), dim3(256), 0, stream>>>(
          xb, w1b, b1, (void*)h1);

  // GEMM2: M=2048, N=1024(HIDDEN), K=4096(INTER) -> out (fp32)
  gemm_bt<MTOK, HIDDEN, INTER, false>
      <<<dim3(MTOK / 128, HIDDEN / 128, NUM_GEMMS), dim3(256), 0, stream>>>(
          h1, w2b, b2, (void*)out);
}